// Round 1
// baseline (1132.865 us; speedup 1.0000x reference)
//
#include <hip/hip_runtime.h>

#define NAG 12
#define NTH 4096
#define NEDGE 132
#define EPW 33   // edges per wave (4 waves x 33 = 132); wave g owns agents 3g..3g+2

__device__ __forceinline__ float silu_f(float z) {
    float e = __expf(-z);
    return z * __builtin_amdgcn_rcpf(1.0f + e);
}

__global__ __launch_bounds__(256) void egnn_fused(
    const float* __restrict__ h0, const float* __restrict__ x0,
    const float* __restrict__ W_embed, const float* __restrict__ b_embed,
    const float* __restrict__ We1, const float* __restrict__ be1,
    const float* __restrict__ We2, const float* __restrict__ be2,
    const float* __restrict__ Wx, const float* __restrict__ bx,
    const float* __restrict__ Wh1, const float* __restrict__ bh1,
    const float* __restrict__ Wh2, const float* __restrict__ bh2,
    const float* __restrict__ w_act, const float* __restrict__ log_std,
    float* __restrict__ out)
{
    // 52 KB total -> 3 blocks/CU
    __shared__ __align__(16) float sS[NEDGE][68]; // s1, then m (edge messages)
    __shared__ float sh[NAG][64];                 // node embedding h
    __shared__ float sHa[NAG][64];                // h @ We1[0:64]   (later reused as t1)
    __shared__ float sHb[NAG][64];                // h @ We1[64:128]
    __shared__ float sAgg[NAG][64];               // segment_sum(m)
    __shared__ float sx[NAG][16];                 // coords, [i][d*4+v], 12 used
    __shared__ float sRad[NEDGE][4];
    __shared__ float sWc[NEDGE][4];

    const int tid  = threadIdx.x;
    const int lane = tid & 63;
    const int g    = tid >> 6;      // wave index 0..3
    const int env  = blockIdx.x;
    const int n0   = env * NAG;

    // ---- load x (contiguous 144 floats per env) ----
    for (int t = tid; t < NAG*12; t += 256) sx[t/12][t%12] = x0[env*NAG*12 + t];

    // ---- embed: h = h0 @ W_embed + b_embed  (wave g does agents 3g..3g+2) ----
    {
        const int ib = g*3;
        float acc0 = b_embed[lane], acc1 = acc0, acc2 = acc0;
        for (int k = 0; k < 32; ++k) {
            float w = W_embed[k*64 + lane];
            acc0 += h0[(n0+ib+0)*32 + k] * w;
            acc1 += h0[(n0+ib+1)*32 + k] * w;
            acc2 += h0[(n0+ib+2)*32 + k] * w;
        }
        sh[ib+0][lane] = acc0; sh[ib+1][lane] = acc1; sh[ib+2][lane] = acc2;
    }
    __syncthreads();

    for (int l = 0; l < 2; ++l) {
        const float* We1l = We1 + l*NEDGE*64;
        const float* be1l = be1 + l*64;
        const float* We2l = We2 + l*64*64;
        const float* be2l = be2 + l*64;
        const float* Wxl  = Wx  + l*64*4;
        const float* bxl  = bx  + l*4;
        const float* Wh1l = Wh1 + l*128*64;
        const float* bh1l = bh1 + l*64;
        const float* Wh2l = Wh2 + l*64*64;
        const float* bh2l = bh2 + l*64;

        // ---- Stage P: Ha = h@We1[0:64], Hb = h@We1[64:128]
        // waves 0,1 -> Ha halves; waves 2,3 -> Hb halves
        {
            const float* W = We1l + ((g >= 2) ? 64*64 : 0);
            float* dst = (g >= 2) ? &sHb[0][0] : &sHa[0][0];
            const int ib = (g & 1) * 6;
            float acc[6] = {0,0,0,0,0,0};
            for (int k = 0; k < 64; ++k) {
                float w = W[k*64 + lane];
                #pragma unroll
                for (int ii = 0; ii < 6; ++ii) acc[ii] += sh[ib+ii][k] * w;
            }
            #pragma unroll
            for (int ii = 0; ii < 6; ++ii) dst[(ib+ii)*64 + lane] = acc[ii];
        }
        // ---- Stage R: radial[e][v] = sum_d (x_i - x_j)^2
        for (int t = tid; t < NEDGE*4; t += 256) {
            int e = t >> 2, v = t & 3;
            int i = e / 11, jj = e - i*11; int j = jj + (jj >= i);
            float r = 0.f;
            #pragma unroll
            for (int d = 0; d < 3; ++d) {
                float df = sx[i][d*4+v] - sx[j][d*4+v];
                r += df*df;
            }
            sRad[e][v] = r;
        }
        __syncthreads();

        // ---- Stage A: s1[e] = silu(Ha[i] + Hb[j] + radial[e]@We1c + be1)
        {
            float wc0 = We1l[128*64 + lane], wc1 = We1l[129*64 + lane];
            float wc2 = We1l[130*64 + lane], wc3 = We1l[131*64 + lane];
            float b1 = be1l[lane];
            for (int e = g*EPW; e < (g+1)*EPW; ++e) {
                int i = e / 11, jj = e - i*11; int j = jj + (jj >= i);
                float z = sHa[i][lane] + sHb[j][lane] + b1
                        + sRad[e][0]*wc0 + sRad[e][1]*wc1
                        + sRad[e][2]*wc2 + sRad[e][3]*wc3;
                sS[e][lane] = silu_f(z);
            }
        }
        __syncthreads();

        // ---- Stage B: m = silu(s1 @ We2 + be2); wave g owns its 33 rows of sS
        float m[EPW];
        {
            #pragma unroll
            for (int ee = 0; ee < EPW; ++ee) m[ee] = 0.f;
            const int e0 = g*EPW;
            for (int k4 = 0; k4 < 16; ++k4) {
                float w0 = We2l[(4*k4+0)*64 + lane];
                float w1 = We2l[(4*k4+1)*64 + lane];
                float w2 = We2l[(4*k4+2)*64 + lane];
                float w3 = We2l[(4*k4+3)*64 + lane];
                #pragma unroll
                for (int ee = 0; ee < EPW; ++ee) {
                    const float4 s = *(const float4*)(&sS[e0+ee][4*k4]);
                    m[ee] += s.x*w0 + s.y*w1 + s.z*w2 + s.w*w3;
                }
            }
            float b2 = be2l[lane];
            #pragma unroll
            for (int ee = 0; ee < EPW; ++ee) m[ee] = silu_f(m[ee] + b2);
        }
        __syncthreads();            // everyone done reading sS (s1)
        {
            const int e0 = g*EPW;
            #pragma unroll
            for (int ee = 0; ee < EPW; ++ee) sS[e0+ee][lane] = m[ee]; // sS now holds m
            // agg[i] = sum_j m[e(i,j)] ; wave g exclusively owns i = 3g..3g+2
            #pragma unroll
            for (int ii = 0; ii < 3; ++ii) {
                float a = 0.f;
                #pragma unroll
                for (int jj = 0; jj < 11; ++jj) a += m[ii*11 + jj];
                sAgg[g*3+ii][lane] = a;
            }
        }
        __syncthreads();

        // ---- Stage C1: wc[e][v] = m[e] @ Wx + bx  (thread: v=tid&3, e0=tid>>2)
        {
            const int v = tid & 3, e0 = tid >> 2;
            float acc0 = bxl[v], acc1 = acc0, acc2 = acc0;
            for (int k4 = 0; k4 < 16; ++k4) {
                float w0 = Wxl[(4*k4+0)*4 + v], w1 = Wxl[(4*k4+1)*4 + v];
                float w2 = Wxl[(4*k4+2)*4 + v], w3 = Wxl[(4*k4+3)*4 + v];
                float4 sa = *(const float4*)(&sS[e0][4*k4]);
                acc0 += sa.x*w0 + sa.y*w1 + sa.z*w2 + sa.w*w3;
                float4 sb = *(const float4*)(&sS[e0+64][4*k4]);
                acc1 += sb.x*w0 + sb.y*w1 + sb.z*w2 + sb.w*w3;
                if (e0 < 4) {
                    float4 sc = *(const float4*)(&sS[e0+128][4*k4]);
                    acc2 += sc.x*w0 + sc.y*w1 + sc.z*w2 + sc.w*w3;
                }
            }
            sWc[e0][v] = acc0;
            sWc[e0+64][v] = acc1;
            if (e0 < 4) sWc[e0+128][v] = acc2;
        }
        __syncthreads();

        // ---- Stage C2: x[i] += (1/11) * sum_{j!=i} (x_i - x_j) * wc[e][v]
        {
            const int xi = tid >> 4, dv = tid & 15;
            const bool act = (xi < 12) && (dv < 12);
            float xacc = 0.f;
            if (act) {
                const int v = dv & 3;
                float xiv = sx[xi][dv];
                #pragma unroll
                for (int j = 0; j < 12; ++j) {
                    if (j == xi) continue;
                    int e = xi*11 + j - (j > xi);
                    xacc += (xiv - sx[j][dv]) * sWc[e][v];
                }
            }
            __syncthreads();
            if (act) sx[xi][dv] += xacc * (1.0f/11.0f);
        }

        // ---- Stage D1: t1 = silu([h,agg] @ Wh1 + bh1) -> reuse sHa
        {
            const int ib = g*3;
            float acc0 = bh1l[lane], acc1 = acc0, acc2 = acc0;
            for (int k = 0; k < 64; ++k) {
                float w = Wh1l[k*64 + lane];
                acc0 += sh[ib+0][k]*w; acc1 += sh[ib+1][k]*w; acc2 += sh[ib+2][k]*w;
            }
            for (int k = 0; k < 64; ++k) {
                float w = Wh1l[(64+k)*64 + lane];
                acc0 += sAgg[ib+0][k]*w; acc1 += sAgg[ib+1][k]*w; acc2 += sAgg[ib+2][k]*w;
            }
            sHa[ib+0][lane] = silu_f(acc0);
            sHa[ib+1][lane] = silu_f(acc1);
            sHa[ib+2][lane] = silu_f(acc2);
        }
        __syncthreads();

        // ---- Stage D2: h += t1 @ Wh2 + bh2
        {
            const int ib = g*3;
            float acc0 = bh2l[lane], acc1 = acc0, acc2 = acc0;
            for (int k = 0; k < 64; ++k) {
                float w = Wh2l[k*64 + lane];
                acc0 += sHa[ib+0][k]*w; acc1 += sHa[ib+1][k]*w; acc2 += sHa[ib+2][k]*w;
            }
            sh[ib+0][lane] += acc0; sh[ib+1][lane] += acc1; sh[ib+2][lane] += acc2;
        }
        __syncthreads();
    }

    // ---- epilogue: mu = x . w_act ; log_probs constant per d ----
    if (tid < NAG*3) {
        const int i = tid/3, d = tid - i*3;
        float mu = 0.f;
        #pragma unroll
        for (int v = 0; v < 4; ++v) mu += sx[i][d*4+v] * w_act[v];
        out[env*(NAG*3) + tid] = mu;
        out[NTH*NAG*3 + env*(NAG*3) + tid] = -log_std[d] - 0.9189385332046727f;
    }
}

extern "C" void kernel_launch(void* const* d_in, const int* in_sizes, int n_in,
                              void* d_out, int out_size, void* d_ws, size_t ws_size,
                              hipStream_t stream) {
    // inputs: h0,x0,W_embed,b_embed,We1,be1,We2,be2,Wx,bx,Wh1,bh1,Wh2,bh2,w_act,log_std,row,col
    // row/col are structurally known (fully-connected 12-agent graphs) and unused.
    egnn_fused<<<dim3(NTH), dim3(256), 0, stream>>>(
        (const float*)d_in[0],  (const float*)d_in[1],  (const float*)d_in[2],
        (const float*)d_in[3],  (const float*)d_in[4],  (const float*)d_in[5],
        (const float*)d_in[6],  (const float*)d_in[7],  (const float*)d_in[8],
        (const float*)d_in[9],  (const float*)d_in[10], (const float*)d_in[11],
        (const float*)d_in[12], (const float*)d_in[13], (const float*)d_in[14],
        (const float*)d_in[15], (float*)d_out);
}

// Round 2
// 364.791 us; speedup vs baseline: 3.1055x; 3.1055x over previous
//
#include <hip/hip_runtime.h>

#define NAG 12
#define NTH 4096
#define NEDGE 132

typedef __bf16  bf16_8 __attribute__((ext_vector_type(8)));
typedef float   f32x4  __attribute__((ext_vector_type(4)));

#define MFMA(a, b, c) __builtin_amdgcn_mfma_f32_16x16x32_bf16((a), (b), (c), 0, 0, 0)

__device__ __forceinline__ float silu_f(float z) {
    float e = __expf(-z);
    return z * __builtin_amdgcn_rcpf(1.0f + e);
}

// B-fragment for mfma_f32_16x16x32_bf16: lane holds B[k = ks*32 + quad*8 + j][n],
// n = nbase + (lane&15). W is row-major [K][64], fp32 -> bf16 on the fly.
__device__ __forceinline__ bf16_8 loadB64(const float* __restrict__ W, int kbase, int n) {
    bf16_8 b;
    #pragma unroll
    for (int j = 0; j < 8; ++j) b[j] = (__bf16)W[(kbase + j) * 64 + n];
    return b;
}

// A-fragment from an fp32 LDS buffer with row stride `ldf` floats (kbase multiple of 8).
__device__ __forceinline__ bf16_8 loadA_f32(const float* S, int row, int ldf, int kbase) {
    const float4* p = (const float4*)(S + row * ldf + kbase);
    float4 u = p[0], v = p[1];
    bf16_8 a;
    a[0] = (__bf16)u.x; a[1] = (__bf16)u.y; a[2] = (__bf16)u.z; a[3] = (__bf16)u.w;
    a[4] = (__bf16)v.x; a[5] = (__bf16)v.y; a[6] = (__bf16)v.z; a[7] = (__bf16)v.w;
    return a;
}

__global__ __launch_bounds__(256) void egnn_mfma(
    const float* __restrict__ h0, const float* __restrict__ x0,
    const float* __restrict__ W_embed, const float* __restrict__ b_embed,
    const float* __restrict__ We1, const float* __restrict__ be1,
    const float* __restrict__ We2, const float* __restrict__ be2,
    const float* __restrict__ Wx, const float* __restrict__ bx,
    const float* __restrict__ Wh1, const float* __restrict__ bh1,
    const float* __restrict__ Wh2, const float* __restrict__ bh2,
    const float* __restrict__ w_act, const float* __restrict__ log_std,
    float* __restrict__ out)
{
    // LDS: 19008*2 (bf16 s1/m, row stride 72) + 3264*3 (fp32 node bufs, stride 68)
    //      + 768 + 2112*2 = 52800 B -> 3 blocks/CU
    __shared__ __align__(16) __bf16 sS1[NEDGE * 72];   // s1 (bf16)
    __shared__ __align__(16) __bf16 sM [NEDGE * 72];   // m  (bf16)
    __shared__ __align__(16) float  sh_f [NAG * 68];   // h (fp32 residual)
    __shared__ __align__(16) float  sHa_f[NAG * 68];   // Ha, later t1
    __shared__ __align__(16) float  sHb_f[NAG * 68];   // Hb, later agg
    __shared__ __align__(16) float  sx[NAG][16];       // coords [i][d*4+v]
    __shared__ __align__(16) float  sRad[NEDGE * 4];
    __shared__ __align__(16) float  sWc [NEDGE * 4];

    const int tid  = threadIdx.x;
    const int lane = tid & 63;
    const int g    = tid >> 6;          // wave 0..3 == n-tile for node GEMMs
    const int q    = lane >> 4;         // quad
    const int n16  = lane & 15;
    const int col  = g * 16 + n16;      // this lane's output column in 64-wide GEMMs
    const int rowA = (n16 < NAG) ? n16 : (NAG - 1);  // clamped A row for node GEMMs
    const int env  = blockIdx.x;
    const int n0   = env * NAG;

    // ---- load x ----
    for (int t = tid; t < NAG * 12; t += 256) sx[t / 12][t % 12] = x0[env * NAG * 12 + t];

    // ---- embed: h = h0 @ W_embed + b_embed (MFMA, K=32) ----
    {
        const float* hp = h0 + (n0 + rowA) * 32 + q * 8;
        float4 u = *(const float4*)hp, v = *(const float4*)(hp + 4);
        bf16_8 a;
        a[0]=(__bf16)u.x; a[1]=(__bf16)u.y; a[2]=(__bf16)u.z; a[3]=(__bf16)u.w;
        a[4]=(__bf16)v.x; a[5]=(__bf16)v.y; a[6]=(__bf16)v.z; a[7]=(__bf16)v.w;
        bf16_8 b = loadB64(W_embed, q * 8, col);
        f32x4 acc = {0.f, 0.f, 0.f, 0.f};
        acc = MFMA(a, b, acc);
        float bias = b_embed[col];
        #pragma unroll
        for (int r = 0; r < 4; ++r) {
            int rr = q * 4 + r;
            if (rr < NAG) sh_f[rr * 68 + col] = acc[r] + bias;
        }
    }
    __syncthreads();

    for (int l = 0; l < 2; ++l) {
        const float* We1l = We1 + l * NEDGE * 64;
        const float* be1l = be1 + l * 64;
        const float* We2l = We2 + l * 64 * 64;
        const float* be2l = be2 + l * 64;
        const float* Wxl  = Wx  + l * 64 * 4;
        const float* bxl  = bx  + l * 4;
        const float* Wh1l = Wh1 + l * 128 * 64;
        const float* bh1l = bh1 + l * 64;
        const float* Wh2l = Wh2 + l * 64 * 64;
        const float* bh2l = bh2 + l * 64;

        // ---- S1: Ha = h@We1[0:64], Hb = h@We1[64:128]  (MFMA) + radial ----
        {
            bf16_8 a0 = loadA_f32(sh_f, rowA, 68, q * 8);
            bf16_8 a1 = loadA_f32(sh_f, rowA, 68, 32 + q * 8);
            bf16_8 b0 = loadB64(We1l,            q * 8, col);
            bf16_8 b1 = loadB64(We1l,       32 + q * 8, col);
            bf16_8 c0 = loadB64(We1l + 64*64,    q * 8, col);
            bf16_8 c1 = loadB64(We1l + 64*64, 32+q * 8, col);
            f32x4 accA = {0.f,0.f,0.f,0.f}, accB = {0.f,0.f,0.f,0.f};
            accA = MFMA(a0, b0, accA); accA = MFMA(a1, b1, accA);
            accB = MFMA(a0, c0, accB); accB = MFMA(a1, c1, accB);
            #pragma unroll
            for (int r = 0; r < 4; ++r) {
                int rr = q * 4 + r;
                if (rr < NAG) { sHa_f[rr * 68 + col] = accA[r]; sHb_f[rr * 68 + col] = accB[r]; }
            }
        }
        // radial[e][v] = sum_d (x_i - x_j)^2
        for (int t = tid; t < NEDGE * 4; t += 256) {
            int e = t >> 2, v = t & 3;
            int i = e / 11, jj = e - i * 11; int j = jj + (jj >= i);
            float r = 0.f;
            #pragma unroll
            for (int d = 0; d < 3; ++d) {
                float df = sx[i][d * 4 + v] - sx[j][d * 4 + v];
                r += df * df;
            }
            sRad[e * 4 + v] = r;
        }
        __syncthreads();

        // ---- S2: s1[e] = silu(Ha[i] + Hb[j] + rad@We1c + be1) -> bf16 LDS ----
        {
            float w0 = We1l[128 * 64 + lane], w1 = We1l[129 * 64 + lane];
            float w2 = We1l[130 * 64 + lane], w3 = We1l[131 * 64 + lane];
            float b1v = be1l[lane];
            #pragma unroll
            for (int ii = 0; ii < 3; ++ii) {
                int i = g * 3 + ii;
                float hai = sHa_f[i * 68 + lane] + b1v;
                #pragma unroll
                for (int jj = 0; jj < 11; ++jj) {
                    int e = i * 11 + jj;
                    int j = jj + (jj >= i);
                    const float4 rad = *(const float4*)(sRad + e * 4);
                    float z = hai + sHb_f[j * 68 + lane]
                            + rad.x * w0 + rad.y * w1 + rad.z * w2 + rad.w * w3;
                    sS1[e * 72 + lane] = (__bf16)silu_f(z);
                }
            }
        }
        __syncthreads();

        // ---- S3: m = silu(s1 @ We2 + be2)  (MFMA, 9 M-tiles, wave g = n-tile g) ----
        {
            bf16_8 b0 = loadB64(We2l,      q * 8, col);
            bf16_8 b1 = loadB64(We2l, 32 + q * 8, col);
            float bias = be2l[col];
            for (int mt = 0; mt < 9; ++mt) {
                int row = mt * 16 + n16; int rc = row < (NEDGE - 1) ? row : (NEDGE - 1);
                bf16_8 a0 = *(const bf16_8*)(sS1 + rc * 72 + q * 8);
                bf16_8 a1 = *(const bf16_8*)(sS1 + rc * 72 + 32 + q * 8);
                f32x4 acc = {0.f,0.f,0.f,0.f};
                acc = MFMA(a0, b0, acc); acc = MFMA(a1, b1, acc);
                #pragma unroll
                for (int r = 0; r < 4; ++r) {
                    int rr = mt * 16 + q * 4 + r;
                    if (rr < NEDGE) sM[rr * 72 + col] = (__bf16)silu_f(acc[r] + bias);
                }
            }
        }
        __syncthreads();

        // ---- S4: wc = m@Wx + bx ; agg = segment-rowsum(m) ----
        {
            const int v = tid & 3, e0 = tid >> 2;
            float acc0 = bxl[v], acc1 = acc0, acc2 = acc0;
            for (int k8 = 0; k8 < 8; ++k8) {
                float w[8];
                #pragma unroll
                for (int j = 0; j < 8; ++j) w[j] = Wxl[(k8 * 8 + j) * 4 + v];
                bf16_8 s0 = *(const bf16_8*)(sM + e0 * 72 + k8 * 8);
                bf16_8 s1v = *(const bf16_8*)(sM + (e0 + 64) * 72 + k8 * 8);
                #pragma unroll
                for (int j = 0; j < 8; ++j) { acc0 += (float)s0[j] * w[j]; acc1 += (float)s1v[j] * w[j]; }
                if (e0 < 4) {
                    bf16_8 s2 = *(const bf16_8*)(sM + (e0 + 128) * 72 + k8 * 8);
                    #pragma unroll
                    for (int j = 0; j < 8; ++j) acc2 += (float)s2[j] * w[j];
                }
            }
            sWc[e0 * 4 + v] = acc0;
            sWc[(e0 + 64) * 4 + v] = acc1;
            if (e0 < 4) sWc[(e0 + 128) * 4 + v] = acc2;
        }
        {   // agg into sHb_f (Hb is dead after S2)
            #pragma unroll
            for (int ii = 0; ii < 3; ++ii) {
                int i = g * 3 + ii;
                float a = 0.f;
                #pragma unroll
                for (int jj = 0; jj < 11; ++jj) a += (float)sM[(i * 11 + jj) * 72 + lane];
                sHb_f[i * 68 + lane] = a;
            }
        }
        __syncthreads();

        // ---- S5: xacc (coord update numerator) + t1 = silu([h,agg]@Wh1 + bh1) ----
        const int xi = tid >> 4, dv = tid & 15;
        const bool act = (xi < NAG) && (dv < 12);
        float xacc = 0.f;
        if (act) {
            const int v = dv & 3;
            float xiv = sx[xi][dv];
            #pragma unroll
            for (int j = 0; j < NAG; ++j) {
                if (j == xi) continue;
                int e = xi * 11 + j - (j > xi);
                xacc += (xiv - sx[j][dv]) * sWc[e * 4 + v];
            }
        }
        {
            bf16_8 a0 = loadA_f32(sh_f,  rowA, 68,      q * 8);
            bf16_8 a1 = loadA_f32(sh_f,  rowA, 68, 32 + q * 8);
            bf16_8 a2 = loadA_f32(sHb_f, rowA, 68,      q * 8);   // agg
            bf16_8 a3 = loadA_f32(sHb_f, rowA, 68, 32 + q * 8);
            bf16_8 b0 = loadB64(Wh1l,                 q * 8, col);
            bf16_8 b1 = loadB64(Wh1l,            32 + q * 8, col);
            bf16_8 b2 = loadB64(Wh1l + 64 * 64,       q * 8, col);
            bf16_8 b3 = loadB64(Wh1l + 64 * 64,  32 + q * 8, col);
            f32x4 acc = {0.f,0.f,0.f,0.f};
            acc = MFMA(a0, b0, acc); acc = MFMA(a1, b1, acc);
            acc = MFMA(a2, b2, acc); acc = MFMA(a3, b3, acc);
            float bias = bh1l[col];
            #pragma unroll
            for (int r = 0; r < 4; ++r) {
                int rr = q * 4 + r;
                if (rr < NAG) sHa_f[rr * 68 + col] = silu_f(acc[r] + bias);  // t1
            }
        }
        __syncthreads();

        // ---- S6: x += xacc/11 ; h += t1@Wh2 + bh2 ----
        if (act) sx[xi][dv] += xacc * (1.0f / 11.0f);
        {
            bf16_8 a0 = loadA_f32(sHa_f, rowA, 68,      q * 8);
            bf16_8 a1 = loadA_f32(sHa_f, rowA, 68, 32 + q * 8);
            bf16_8 b0 = loadB64(Wh2l,      q * 8, col);
            bf16_8 b1 = loadB64(Wh2l, 32 + q * 8, col);
            f32x4 acc = {0.f,0.f,0.f,0.f};
            acc = MFMA(a0, b0, acc); acc = MFMA(a1, b1, acc);
            float bias = bh2l[col];
            #pragma unroll
            for (int r = 0; r < 4; ++r) {
                int rr = q * 4 + r;
                if (rr < NAG) sh_f[rr * 68 + col] += acc[r] + bias;
            }
        }
        __syncthreads();
    }

    // ---- epilogue ----
    if (tid < NAG * 3) {
        const int i = tid / 3, d = tid - i * 3;
        float mu = 0.f;
        #pragma unroll
        for (int v = 0; v < 4; ++v) mu += sx[i][d * 4 + v] * w_act[v];
        out[env * (NAG * 3) + tid] = mu;
        out[NTH * NAG * 3 + env * (NAG * 3) + tid] = -log_std[d] - 0.9189385332046727f;
    }
}

extern "C" void kernel_launch(void* const* d_in, const int* in_sizes, int n_in,
                              void* d_out, int out_size, void* d_ws, size_t ws_size,
                              hipStream_t stream) {
    // inputs: h0,x0,W_embed,b_embed,We1,be1,We2,be2,Wx,bx,Wh1,bh1,Wh2,bh2,w_act,log_std,row,col
    // row/col are structurally known (fully-connected 12-agent graphs) and unused.
    egnn_mfma<<<dim3(NTH), dim3(256), 0, stream>>>(
        (const float*)d_in[0],  (const float*)d_in[1],  (const float*)d_in[2],
        (const float*)d_in[3],  (const float*)d_in[4],  (const float*)d_in[5],
        (const float*)d_in[6],  (const float*)d_in[7],  (const float*)d_in[8],
        (const float*)d_in[9],  (const float*)d_in[10], (const float*)d_in[11],
        (const float*)d_in[12], (const float*)d_in[13], (const float*)d_in[14],
        (const float*)d_in[15], (float*)d_out);
}